// Round 1
// baseline (821.594 us; speedup 1.0000x reference)
//
#include <hip/hip_runtime.h>

typedef unsigned short u16;
typedef short short8 __attribute__((ext_vector_type(8)));
typedef float f32x4 __attribute__((ext_vector_type(4)));

#define B_ 8
#define T_ 1024
#define E_ 1024
#define H_ 16
#define D_ 64
#define BH_ 128

__device__ __forceinline__ float ftanh(float x){
    x = fminf(9.0f, fmaxf(-9.0f, x));
    float e2 = __expf(2.0f * x);
    return (e2 - 1.0f) / (e2 + 1.0f);
}

__device__ __forceinline__ u16 f2bf(float x){
    union { float f; unsigned int u; } v; v.f = x;
    unsigned int r = v.u + 0x7fffu + ((v.u >> 16) & 1u);
    return (u16)(r >> 16);
}

// ---------------------------------------------------------------------------
// Kernel 1: fused q/v projection (+bf16 cast) and RNN key generation.
// Blocks [0,128): one per (b,h), 1 active wave, sequential 1023-step RNN.
// Blocks [128,...): one thread per (b,h,t,e) output of q_proj and v_proj.
// ---------------------------------------------------------------------------
__global__ __launch_bounds__(256) void proj_rnn_kernel(
    const float* __restrict__ src, const float* __restrict__ tgt,
    const float* __restrict__ Wq,  const float* __restrict__ Wv,
    const float* __restrict__ Wih, const float* __restrict__ Whh,
    const float* __restrict__ bih, const float* __restrict__ bhh,
    u16* __restrict__ qbf, u16* __restrict__ vbf, u16* __restrict__ nwbf)
{
    int bid = blockIdx.x;
    if (bid < BH_) {
        // ---- RNN role ----
        __shared__ __align__(16) float hb[2][D_];
        int b = bid >> 4, h = bid & 15;
        int e = threadIdx.x;
        bool act = (e < D_);
        float m[D_];
        float c = 0.f;
        if (act) {
            const float* wih_row = Wih + ((size_t)h * D_ + e) * D_;
            c = bih[h * D_ + e] + bhh[h * D_ + e];
            #pragma unroll
            for (int d = 0; d < D_; ++d) m[d] = wih_row[d];
            hb[0][e] = tgt[(size_t)b * T_ * E_ + h * D_ + e];  // k0 = target[b,0,h,:]
        }
        __syncthreads();
        u16* nwp = nwbf + (size_t)bid * T_ * D_;
        if (act) {
            float s = c;
            const float4* h4 = (const float4*)hb[0];
            #pragma unroll
            for (int d4 = 0; d4 < D_ / 4; ++d4) {
                float4 x = h4[d4];
                s += m[4*d4+0]*x.x + m[4*d4+1]*x.y + m[4*d4+2]*x.z + m[4*d4+3]*x.w;
            }
            float hv = ftanh(s);
            nwp[e] = f2bf(hv);
            hb[1][e] = hv;
            const float* whh_row = Whh + ((size_t)h * D_ + e) * D_;
            #pragma unroll
            for (int d = 0; d < D_; ++d) m[d] += whh_row[d];
        }
        __syncthreads();
        int p = 1;
        #pragma unroll 1
        for (int t = 1; t < T_; ++t) {
            if (act) {
                float s = c;
                const float4* h4 = (const float4*)hb[p];
                #pragma unroll
                for (int d4 = 0; d4 < D_ / 4; ++d4) {
                    float4 x = h4[d4];
                    s += m[4*d4+0]*x.x + m[4*d4+1]*x.y + m[4*d4+2]*x.z + m[4*d4+3]*x.w;
                }
                float hv = ftanh(s);
                hb[p ^ 1][e] = hv;
                nwp[(size_t)t * D_ + e] = f2bf(hv);
            }
            p ^= 1;
            __syncthreads();
        }
    } else {
        // ---- projection role: one thread per (b,h,t,e) ----
        int id = (bid - BH_) * 256 + threadIdx.x;       // 0 .. B*H*T*D-1
        int e = id & 63;
        int t = (id >> 6) & 1023;
        int h = (id >> 16) & 15;
        int b = id >> 20;
        const float* srow = src + ((size_t)b * T_ + t) * E_ + h * D_;
        const float* trow = tgt + ((size_t)b * T_ + t) * E_ + h * D_;
        const float* wq = Wq + (size_t)h * D_ * D_ + e;  // stride 64 over d
        const float* wv = Wv + (size_t)h * D_ * D_ + e;
        float aq = 0.f, av = 0.f;
        #pragma unroll 8
        for (int d = 0; d < D_; ++d) {
            aq += srow[d] * wq[(size_t)d * D_];
            av += trow[d] * wv[(size_t)d * D_];
        }
        size_t o = (((size_t)b * H_ + h) * T_ + t) * D_ + e;
        qbf[o] = f2bf(aq * (1.0f / 256.0f));  // fold 1/(sqrt(D)*sqrt(T)) into q
        vbf[o] = f2bf(av);
    }
}

// ---------------------------------------------------------------------------
// Kernel 2: flash attention, bf16 MFMA 16x16x32.
// Block = 256 threads (4 waves); wave w owns q rows [16w,16w+16) of a 64-row
// Q tile. K tiles of 64 keys. Online softmax per 16-lane quad via shfl_xor.
// LDS layouts are 16B-chunk XOR-swizzled: element (row,col) of a 64-wide u16
// row lives at row*64 + ((col>>3 ^ (row&7))*8) + (col&7).
// ---------------------------------------------------------------------------
#define MFMA16(a, b, c) __builtin_amdgcn_mfma_f32_16x16x32_bf16(a, b, c, 0, 0, 0)

__global__ __launch_bounds__(256) void attn_kernel(
    const u16* __restrict__ qbf,   // [BH][T][64], pre-scaled 1/256
    const u16* __restrict__ kbf,   // nw states  [BH][T][64]
    const u16* __restrict__ vbf,   // [BH][T][64]
    float* __restrict__ ao)        // [BH][T][64] fp32, softmax-normalized
{
    __shared__ __align__(16) u16 Klds[64 * 64];     // keys row-major
    __shared__ __align__(16) u16 Vlds[64 * 64];     // V^T: row=d, col=key
    __shared__ __align__(16) u16 Plds[4][16 * 64];  // per-wave P, row=q, col=key

    const int tid  = threadIdx.x;
    const int lane = tid & 63;
    const int w    = tid >> 6;
    const int l15  = lane & 15;
    const int quad = lane >> 4;
    const int sw   = lane & 7;          // == (row&7) for all rows used below
    const int bh   = blockIdx.y;
    const int qt   = blockIdx.x;

    const size_t base = (size_t)bh * T_ * D_;

    // persistent Q A-fragments: A[m=l15][k=quad*8+j (+32)]
    short8 aq0, aq1;
    {
        int qrow = qt * 64 + w * 16 + l15;
        const short8* qp = (const short8*)(qbf + base + (size_t)qrow * 64 + quad * 8);
        aq0 = qp[0];
        aq1 = qp[4];   // +32 elements
    }

    f32x4 oacc[4];
    #pragma unroll
    for (int i = 0; i < 4; ++i) oacc[i] = (f32x4){0.f, 0.f, 0.f, 0.f};
    float mrun[4], lrun[4];
    #pragma unroll
    for (int r = 0; r < 4; ++r) { mrun[r] = -1e30f; lrun[r] = 0.f; }

    u16* Pw = Plds[w];

    #pragma unroll 1
    for (int kt = 0; kt < 16; ++kt) {
        // ---- stage K (swizzled row-major) and V (transposed, swizzled) ----
        #pragma unroll
        for (int i = 0; i < 2; ++i) {
            int ch = tid + 256 * i;          // 512 chunks of 8 u16
            int r = ch >> 3, cc = ch & 7;
            short8 val = *(const short8*)(kbf + base + (size_t)(kt * 64 + r) * 64 + cc * 8);
            *(short8*)&Klds[r * 64 + ((cc ^ (r & 7)) * 8)] = val;
        }
        #pragma unroll
        for (int i = 0; i < 2; ++i) {
            int ch = tid + 256 * i;
            int r = ch >> 3, cc = ch & 7;    // key row r, d cols cc*8..cc*8+7
            short8 val = *(const short8*)(vbf + base + (size_t)(kt * 64 + r) * 64 + cc * 8);
            #pragma unroll
            for (int j = 0; j < 8; ++j) {
                int d = cc * 8 + j;
                Vlds[d * 64 + (((r >> 3) ^ (d & 7)) * 8) + (r & 7)] = (u16)val[j];
            }
        }
        __syncthreads();

        // ---- S = Q K^T : 4 key subtiles x 2 k-chunks ----
        f32x4 sacc[4];
        #pragma unroll
        for (int u = 0; u < 4; ++u) {
            sacc[u] = (f32x4){0.f, 0.f, 0.f, 0.f};
            int row = 16 * u + l15;
            short8 bk0 = *(const short8*)&Klds[row * 64 + (((quad + 0) ^ sw) * 8)];
            short8 bk1 = *(const short8*)&Klds[row * 64 + (((quad + 4) ^ sw) * 8)];
            sacc[u] = MFMA16(aq0, bk0, sacc[u]);
            sacc[u] = MFMA16(aq1, bk1, sacc[u]);
        }

        // ---- online softmax (rows = quad*4+r, cols spread over 16 lanes) ----
        float al[4];
        float pX[4][4];                       // [u][r]
        #pragma unroll
        for (int r = 0; r < 4; ++r) {
            float rm = fmaxf(fmaxf(sacc[0][r], sacc[1][r]), fmaxf(sacc[2][r], sacc[3][r]));
            #pragma unroll
            for (int off = 1; off < 16; off <<= 1)
                rm = fmaxf(rm, __shfl_xor(rm, off, 16));
            float mn = fmaxf(mrun[r], rm);
            al[r] = __expf(mrun[r] - mn);
            mrun[r] = mn;
            float rs = 0.f;
            #pragma unroll
            for (int u = 0; u < 4; ++u) {
                float pv = __expf(sacc[u][r] - mn);
                pX[u][r] = pv;
                rs += pv;
            }
            #pragma unroll
            for (int off = 1; off < 16; off <<= 1)
                rs += __shfl_xor(rs, off, 16);
            lrun[r] = lrun[r] * al[r] + rs;
        }
        #pragma unroll
        for (int u = 0; u < 4; ++u)
            #pragma unroll
            for (int r = 0; r < 4; ++r) oacc[u][r] *= al[r];

        // ---- P -> per-wave LDS (C-layout -> A-fragment layout) ----
        #pragma unroll
        for (int u = 0; u < 4; ++u) {
            int col = 16 * u + l15;
            #pragma unroll
            for (int r = 0; r < 4; ++r) {
                int row = quad * 4 + r;
                Pw[row * 64 + (((col >> 3) ^ (row & 7)) * 8) + (col & 7)] = f2bf(pX[u][r]);
            }
        }
        // same-wave LDS RAW: compiler inserts lgkmcnt wait; no barrier needed.

        // ---- O += P V ----
        #pragma unroll
        for (int kc = 0; kc < 2; ++kc) {
            short8 ap = *(const short8*)&Pw[l15 * 64 + (((quad + 4 * kc) ^ sw) * 8)];
            #pragma unroll
            for (int nt = 0; nt < 4; ++nt) {
                int drow = 16 * nt + l15;
                short8 bv = *(const short8*)&Vlds[drow * 64 + (((quad + 4 * kc) ^ sw) * 8)];
                oacc[nt] = MFMA16(ap, bv, oacc[nt]);
            }
        }
        __syncthreads();   // protect Klds/Vlds before next tile's staging
    }

    // ---- epilogue: normalize and store ----
    #pragma unroll
    for (int nt = 0; nt < 4; ++nt) {
        #pragma unroll
        for (int r = 0; r < 4; ++r) {
            int qg = qt * 64 + w * 16 + quad * 4 + r;
            int d  = 16 * nt + l15;
            ao[base + (size_t)qg * 64 + d] = oacc[nt][r] / lrun[r];
        }
    }
}

// ---------------------------------------------------------------------------
// Kernel 3: output projection out[b,t,h*64+e] = sum_d ao[b,h,t,d]*Wo[h,d,e]
// ---------------------------------------------------------------------------
__global__ __launch_bounds__(256) void oproj_kernel(
    const float* __restrict__ ao, const float* __restrict__ Wo,
    float* __restrict__ out)
{
    int id = blockIdx.x * 256 + threadIdx.x;
    int e = id & 63;
    int t = (id >> 6) & 1023;
    int h = (id >> 16) & 15;
    int b = id >> 20;
    const float* arow = ao + (((size_t)(b * H_ + h)) * T_ + t) * D_;
    const float* wo = Wo + (size_t)h * D_ * D_ + e;
    float acc = 0.f;
    #pragma unroll 8
    for (int d = 0; d < D_; ++d) acc += arow[d] * wo[(size_t)d * D_];
    out[((size_t)b * T_ + t) * E_ + h * D_ + e] = acc;
}

// ---------------------------------------------------------------------------
extern "C" void kernel_launch(void* const* d_in, const int* in_sizes, int n_in,
                              void* d_out, int out_size, void* d_ws, size_t ws_size,
                              hipStream_t stream)
{
    const float* src = (const float*)d_in[0];
    const float* tgt = (const float*)d_in[1];
    const float* Wq  = (const float*)d_in[2];
    const float* Wv  = (const float*)d_in[3];
    const float* Wo  = (const float*)d_in[4];
    const float* Wih = (const float*)d_in[5];
    const float* Whh = (const float*)d_in[6];
    const float* bih = (const float*)d_in[7];
    const float* bhh = (const float*)d_in[8];
    float* out = (float*)d_out;

    char* ws = (char*)d_ws;
    u16*   qbf  = (u16*)(ws);                       // 16 MB bf16
    u16*   vbf  = (u16*)(ws + (size_t)16 * 1024 * 1024);
    u16*   nwbf = (u16*)(ws + (size_t)32 * 1024 * 1024);
    float* ao   = (float*)(ws + (size_t)48 * 1024 * 1024);  // 32 MB fp32

    (void)in_sizes; (void)n_in; (void)out_size; (void)ws_size;

    // blocks [0,128) = RNN chains; [128, 128+32768) = q/v projection
    proj_rnn_kernel<<<dim3(BH_ + 32768), 256, 0, stream>>>(
        src, tgt, Wq, Wv, Wih, Whh, bih, bhh, qbf, vbf, nwbf);
    attn_kernel<<<dim3(16, BH_), 256, 0, stream>>>(qbf, nwbf, vbf, ao);
    oproj_kernel<<<32768, 256, 0, stream>>>(ao, Wo, out);
}

// Round 2
// 659.890 us; speedup vs baseline: 1.2450x; 1.2450x over previous
//
#include <hip/hip_runtime.h>

typedef unsigned short u16;
typedef short short8 __attribute__((ext_vector_type(8)));
typedef float f32x4 __attribute__((ext_vector_type(4)));
typedef float f32x2 __attribute__((ext_vector_type(2)));

#define B_ 8
#define T_ 1024
#define E_ 1024
#define H_ 16
#define D_ 64
#define BH_ 128

__device__ __forceinline__ float ftanh(float x){
    x = fminf(8.0f, fmaxf(-8.0f, x));
    float e2 = __expf(2.0f * x);                       // v_mul + v_exp
    return 1.0f - 2.0f * __builtin_amdgcn_rcpf(e2 + 1.0f);
}

__device__ __forceinline__ u16 f2bf(float x){
    union { float f; unsigned int u; } v; v.f = x;
    unsigned int r = v.u + 0x7fffu + ((v.u >> 16) & 1u);
    return (u16)(r >> 16);
}

// ---------------------------------------------------------------------------
// Kernel 1: fused q/v projection (+bf16 cast) and RNN key generation.
// Blocks [0,128): one per (b,h). RNN runs on wave 0 ONLY (64 lanes, no
// barriers; single-wave LDS ops are issue-ordered). M rows live in VGPRs as
// float2 (v_pk_fma_f32); launch_bounds(256,1) gives the full VGPR budget so
// the allocator does NOT spill (round-1 VGPR=52 => m[] spilled to scratch,
// 1117 cyc/step).
// Blocks [128,...): one thread per (b,h,t,e) output of q_proj and v_proj.
// ---------------------------------------------------------------------------
__global__ __launch_bounds__(256, 1) void proj_rnn_kernel(
    const float* __restrict__ src, const float* __restrict__ tgt,
    const float* __restrict__ Wq,  const float* __restrict__ Wv,
    const float* __restrict__ Wih, const float* __restrict__ Whh,
    const float* __restrict__ bih, const float* __restrict__ bhh,
    u16* __restrict__ qbf, u16* __restrict__ vbf, u16* __restrict__ nwbf)
{
    int bid = blockIdx.x;
    if (bid < BH_) {
        // ---- RNN role: single wave ----
        if (threadIdx.x >= 64) return;
        __shared__ __align__(16) float hb[D_];
        const int b = bid >> 4, h = bid & 15;
        const int e = threadIdx.x;

        const f32x2* wih_row = (const f32x2*)(Wih + ((size_t)h * D_ + e) * D_);
        const f32x2* whh_row = (const f32x2*)(Whh + ((size_t)h * D_ + e) * D_);
        const float c = bih[h * D_ + e] + bhh[h * D_ + e];

        f32x2 m[32];
        #pragma unroll
        for (int i = 0; i < 32; ++i) m[i] = wih_row[i];

        hb[e] = tgt[(size_t)b * T_ * E_ + h * D_ + e];   // k0 = target[b,0,h,:]

        u16* nwp = nwbf + (size_t)bid * T_ * D_;
        const f32x4* h4 = (const f32x4*)hb;

        // ---- step 1: h1 = tanh(Wih k0 + c) ----
        {
            f32x2 a0 = {c, 0.f}, a1 = {0.f, 0.f}, a2 = {0.f, 0.f}, a3 = {0.f, 0.f};
            #pragma unroll
            for (int i = 0; i < 16; i += 2) {
                f32x4 x = h4[i], y = h4[i + 1];
                a0 += m[2*i+0] * (f32x2){x.x, x.y};
                a1 += m[2*i+1] * (f32x2){x.z, x.w};
                a2 += m[2*i+2] * (f32x2){y.x, y.y};
                a3 += m[2*i+3] * (f32x2){y.z, y.w};
            }
            f32x2 tsum = (a0 + a1) + (a2 + a3);
            float hv = ftanh(tsum.x + tsum.y);
            nwp[e] = f2bf(hv);
            hb[e] = hv;
        }
        // subsequent steps use Wih + Whh
        #pragma unroll
        for (int i = 0; i < 32; ++i) m[i] += whh_row[i];

        #pragma unroll 1
        for (int t = 1; t < T_; ++t) {
            f32x2 a0 = {c, 0.f}, a1 = {0.f, 0.f}, a2 = {0.f, 0.f}, a3 = {0.f, 0.f};
            #pragma unroll
            for (int i = 0; i < 16; i += 2) {
                f32x4 x = h4[i], y = h4[i + 1];
                a0 += m[2*i+0] * (f32x2){x.x, x.y};
                a1 += m[2*i+1] * (f32x2){x.z, x.w};
                a2 += m[2*i+2] * (f32x2){y.x, y.y};
                a3 += m[2*i+3] * (f32x2){y.z, y.w};
            }
            f32x2 tsum = (a0 + a1) + (a2 + a3);
            float hv = ftanh(tsum.x + tsum.y);
            nwp[(size_t)t * D_ + e] = f2bf(hv);
            hb[e] = hv;
        }
    } else {
        // ---- projection role: one thread per (b,h,t,e) ----
        int id = (bid - BH_) * 256 + threadIdx.x;       // 0 .. B*H*T*D-1
        int e = id & 63;
        int t = (id >> 6) & 1023;
        int h = (id >> 16) & 15;
        int b = id >> 20;
        const float* srow = src + ((size_t)b * T_ + t) * E_ + h * D_;
        const float* trow = tgt + ((size_t)b * T_ + t) * E_ + h * D_;
        const float* wq = Wq + (size_t)h * D_ * D_ + e;  // stride 64 over d
        const float* wv = Wv + (size_t)h * D_ * D_ + e;
        float aq = 0.f, av = 0.f;
        #pragma unroll 8
        for (int d = 0; d < D_; ++d) {
            aq += srow[d] * wq[(size_t)d * D_];
            av += trow[d] * wv[(size_t)d * D_];
        }
        size_t o = (((size_t)b * H_ + h) * T_ + t) * D_ + e;
        qbf[o] = f2bf(aq * (1.0f / 256.0f));  // fold 1/(sqrt(D)*sqrt(T)) into q
        vbf[o] = f2bf(av);
    }
}

// ---------------------------------------------------------------------------
// Kernel 2: flash attention, bf16 MFMA 16x16x32.
// Block = 256 threads (4 waves); wave w owns q rows [16w,16w+16) of a 64-row
// Q tile. K tiles of 64 keys. Online softmax per 16-lane quad via shfl_xor.
// LDS layouts are 16B-chunk XOR-swizzled: element (row,col) of a 64-wide u16
// row lives at row*64 + ((col>>3 ^ (row&7))*8) + (col&7).
// ---------------------------------------------------------------------------
#define MFMA16(a, b, c) __builtin_amdgcn_mfma_f32_16x16x32_bf16(a, b, c, 0, 0, 0)

__global__ __launch_bounds__(256) void attn_kernel(
    const u16* __restrict__ qbf,   // [BH][T][64], pre-scaled 1/256
    const u16* __restrict__ kbf,   // nw states  [BH][T][64]
    const u16* __restrict__ vbf,   // [BH][T][64]
    float* __restrict__ ao)        // [BH][T][64] fp32, softmax-normalized
{
    __shared__ __align__(16) u16 Klds[64 * 64];     // keys row-major
    __shared__ __align__(16) u16 Vlds[64 * 64];     // V^T: row=d, col=key
    __shared__ __align__(16) u16 Plds[4][16 * 64];  // per-wave P, row=q, col=key

    const int tid  = threadIdx.x;
    const int lane = tid & 63;
    const int w    = tid >> 6;
    const int l15  = lane & 15;
    const int quad = lane >> 4;
    const int sw   = lane & 7;          // == (row&7) for all rows used below
    const int bh   = blockIdx.y;
    const int qt   = blockIdx.x;

    const size_t base = (size_t)bh * T_ * D_;

    // persistent Q A-fragments: A[m=l15][k=quad*8+j (+32)]
    short8 aq0, aq1;
    {
        int qrow = qt * 64 + w * 16 + l15;
        const short8* qp = (const short8*)(qbf + base + (size_t)qrow * 64 + quad * 8);
        aq0 = qp[0];
        aq1 = qp[4];   // +32 elements
    }

    f32x4 oacc[4];
    #pragma unroll
    for (int i = 0; i < 4; ++i) oacc[i] = (f32x4){0.f, 0.f, 0.f, 0.f};
    float mrun[4], lrun[4];
    #pragma unroll
    for (int r = 0; r < 4; ++r) { mrun[r] = -1e30f; lrun[r] = 0.f; }

    u16* Pw = Plds[w];

    #pragma unroll 1
    for (int kt = 0; kt < 16; ++kt) {
        // ---- stage K (swizzled row-major) and V (transposed, swizzled) ----
        #pragma unroll
        for (int i = 0; i < 2; ++i) {
            int ch = tid + 256 * i;          // 512 chunks of 8 u16
            int r = ch >> 3, cc = ch & 7;
            short8 val = *(const short8*)(kbf + base + (size_t)(kt * 64 + r) * 64 + cc * 8);
            *(short8*)&Klds[r * 64 + ((cc ^ (r & 7)) * 8)] = val;
        }
        #pragma unroll
        for (int i = 0; i < 2; ++i) {
            int ch = tid + 256 * i;
            int r = ch >> 3, cc = ch & 7;    // key row r, d cols cc*8..cc*8+7
            short8 val = *(const short8*)(vbf + base + (size_t)(kt * 64 + r) * 64 + cc * 8);
            #pragma unroll
            for (int j = 0; j < 8; ++j) {
                int d = cc * 8 + j;
                Vlds[d * 64 + (((r >> 3) ^ (d & 7)) * 8) + (r & 7)] = (u16)val[j];
            }
        }
        __syncthreads();

        // ---- S = Q K^T : 4 key subtiles x 2 k-chunks ----
        f32x4 sacc[4];
        #pragma unroll
        for (int u = 0; u < 4; ++u) {
            sacc[u] = (f32x4){0.f, 0.f, 0.f, 0.f};
            int row = 16 * u + l15;
            short8 bk0 = *(const short8*)&Klds[row * 64 + (((quad + 0) ^ sw) * 8)];
            short8 bk1 = *(const short8*)&Klds[row * 64 + (((quad + 4) ^ sw) * 8)];
            sacc[u] = MFMA16(aq0, bk0, sacc[u]);
            sacc[u] = MFMA16(aq1, bk1, sacc[u]);
        }

        // ---- online softmax (rows = quad*4+r, cols spread over 16 lanes) ----
        float al[4];
        float pX[4][4];                       // [u][r]
        #pragma unroll
        for (int r = 0; r < 4; ++r) {
            float rm = fmaxf(fmaxf(sacc[0][r], sacc[1][r]), fmaxf(sacc[2][r], sacc[3][r]));
            #pragma unroll
            for (int off = 1; off < 16; off <<= 1)
                rm = fmaxf(rm, __shfl_xor(rm, off, 16));
            float mn = fmaxf(mrun[r], rm);
            al[r] = __expf(mrun[r] - mn);
            mrun[r] = mn;
            float rs = 0.f;
            #pragma unroll
            for (int u = 0; u < 4; ++u) {
                float pv = __expf(sacc[u][r] - mn);
                pX[u][r] = pv;
                rs += pv;
            }
            #pragma unroll
            for (int off = 1; off < 16; off <<= 1)
                rs += __shfl_xor(rs, off, 16);
            lrun[r] = lrun[r] * al[r] + rs;
        }
        #pragma unroll
        for (int u = 0; u < 4; ++u)
            #pragma unroll
            for (int r = 0; r < 4; ++r) oacc[u][r] *= al[r];

        // ---- P -> per-wave LDS (C-layout -> A-fragment layout) ----
        #pragma unroll
        for (int u = 0; u < 4; ++u) {
            int col = 16 * u + l15;
            #pragma unroll
            for (int r = 0; r < 4; ++r) {
                int row = quad * 4 + r;
                Pw[row * 64 + (((col >> 3) ^ (row & 7)) * 8) + (col & 7)] = f2bf(pX[u][r]);
            }
        }
        // same-wave LDS RAW: compiler inserts lgkmcnt wait; no barrier needed.

        // ---- O += P V ----
        #pragma unroll
        for (int kc = 0; kc < 2; ++kc) {
            short8 ap = *(const short8*)&Pw[l15 * 64 + (((quad + 4 * kc) ^ sw) * 8)];
            #pragma unroll
            for (int nt = 0; nt < 4; ++nt) {
                int drow = 16 * nt + l15;
                short8 bv = *(const short8*)&Vlds[drow * 64 + (((quad + 4 * kc) ^ sw) * 8)];
                oacc[nt] = MFMA16(ap, bv, oacc[nt]);
            }
        }
        __syncthreads();   // protect Klds/Vlds before next tile's staging
    }

    // ---- epilogue: normalize and store ----
    #pragma unroll
    for (int nt = 0; nt < 4; ++nt) {
        #pragma unroll
        for (int r = 0; r < 4; ++r) {
            int qg = qt * 64 + w * 16 + quad * 4 + r;
            int d  = 16 * nt + l15;
            ao[base + (size_t)qg * 64 + d] = oacc[nt][r] / lrun[r];
        }
    }
}

// ---------------------------------------------------------------------------
// Kernel 3: output projection out[b,t,h*64+e] = sum_d ao[b,h,t,d]*Wo[h,d,e]
// ---------------------------------------------------------------------------
__global__ __launch_bounds__(256) void oproj_kernel(
    const float* __restrict__ ao, const float* __restrict__ Wo,
    float* __restrict__ out)
{
    int id = blockIdx.x * 256 + threadIdx.x;
    int e = id & 63;
    int t = (id >> 6) & 1023;
    int h = (id >> 16) & 15;
    int b = id >> 20;
    const float* arow = ao + (((size_t)(b * H_ + h)) * T_ + t) * D_;
    const float* wo = Wo + (size_t)h * D_ * D_ + e;
    float acc = 0.f;
    #pragma unroll 8
    for (int d = 0; d < D_; ++d) acc += arow[d] * wo[(size_t)d * D_];
    out[((size_t)b * T_ + t) * E_ + h * D_ + e] = acc;
}

// ---------------------------------------------------------------------------
extern "C" void kernel_launch(void* const* d_in, const int* in_sizes, int n_in,
                              void* d_out, int out_size, void* d_ws, size_t ws_size,
                              hipStream_t stream)
{
    const float* src = (const float*)d_in[0];
    const float* tgt = (const float*)d_in[1];
    const float* Wq  = (const float*)d_in[2];
    const float* Wv  = (const float*)d_in[3];
    const float* Wo  = (const float*)d_in[4];
    const float* Wih = (const float*)d_in[5];
    const float* Whh = (const float*)d_in[6];
    const float* bih = (const float*)d_in[7];
    const float* bhh = (const float*)d_in[8];
    float* out = (float*)d_out;

    char* ws = (char*)d_ws;
    u16*   qbf  = (u16*)(ws);                       // 16 MB bf16
    u16*   vbf  = (u16*)(ws + (size_t)16 * 1024 * 1024);
    u16*   nwbf = (u16*)(ws + (size_t)32 * 1024 * 1024);
    float* ao   = (float*)(ws + (size_t)48 * 1024 * 1024);  // 32 MB fp32

    (void)in_sizes; (void)n_in; (void)out_size; (void)ws_size;

    // blocks [0,128) = RNN chains; [128, 128+32768) = q/v projection
    proj_rnn_kernel<<<dim3(BH_ + 32768), 256, 0, stream>>>(
        src, tgt, Wq, Wv, Wih, Whh, bih, bhh, qbf, vbf, nwbf);
    attn_kernel<<<dim3(16, BH_), 256, 0, stream>>>(qbf, nwbf, vbf, ao);
    oproj_kernel<<<32768, 256, 0, stream>>>(ao, Wo, out);
}

// Round 3
// 517.216 us; speedup vs baseline: 1.5885x; 1.2759x over previous
//
#include <hip/hip_runtime.h>

typedef unsigned short u16;
typedef short short8 __attribute__((ext_vector_type(8)));
typedef float f32x4 __attribute__((ext_vector_type(4)));
typedef float f32x2 __attribute__((ext_vector_type(2)));
typedef _Float16 f16;
typedef f16 f16x2 __attribute__((ext_vector_type(2)));
typedef f16 f16x8 __attribute__((ext_vector_type(8)));

#define B_ 8
#define T_ 1024
#define E_ 1024
#define H_ 16
#define D_ 64
#define BH_ 128

__device__ __forceinline__ float ftanh(float x){
    x = fminf(8.0f, fmaxf(-8.0f, x));
    float e2 = __expf(2.0f * x);
    return 1.0f - 2.0f * __builtin_amdgcn_rcpf(e2 + 1.0f);
}

__device__ __forceinline__ u16 f2h(float x){
    union { f16 h; u16 u; } v; v.h = (f16)x; return v.u;
}

// 8-wide f16 dot with fp32 accumulate (v_dot2_f32_f16 when available)
__device__ __forceinline__ float dot8(f16x8 a, f16x8 b, float acc){
#if __has_builtin(__builtin_amdgcn_fdot2)
    f16x2 a0 = {a[0],a[1]}, a1 = {a[2],a[3]}, a2 = {a[4],a[5]}, a3 = {a[6],a[7]};
    f16x2 b0 = {b[0],b[1]}, b1 = {b[2],b[3]}, b2 = {b[4],b[5]}, b3 = {b[6],b[7]};
    acc = __builtin_amdgcn_fdot2(a0, b0, acc, false);
    acc = __builtin_amdgcn_fdot2(a1, b1, acc, false);
    acc = __builtin_amdgcn_fdot2(a2, b2, acc, false);
    acc = __builtin_amdgcn_fdot2(a3, b3, acc, false);
#else
    #pragma unroll
    for (int i = 0; i < 8; ++i) acc += (float)a[i] * (float)b[i];
#endif
    return acc;
}

__device__ __forceinline__ f16x8 pack8(f32x4 a, f32x4 b){
    f16x8 r;
    r[0]=(f16)a[0]; r[1]=(f16)a[1]; r[2]=(f16)a[2]; r[3]=(f16)a[3];
    r[4]=(f16)b[0]; r[5]=(f16)b[1]; r[6]=(f16)b[2]; r[7]=(f16)b[3];
    return r;
}

// ---------------------------------------------------------------------------
// Kernel 1: fused q/v projection (f16 out) and RNN key generation (f16 out).
// RNN matrix lives in 8 NAMED f16x8 SSA values (no array => no SROA bail, no
// remat-reload: round-2 VGPR=56 proved m[] was reloaded every step).
// h state round-trips LDS as f16 (8 broadcast ds_read_b128 per step).
// ---------------------------------------------------------------------------
__global__ __launch_bounds__(256, 1) void proj_rnn_kernel(
    const float* __restrict__ src, const float* __restrict__ tgt,
    const float* __restrict__ Wq,  const float* __restrict__ Wv,
    const float* __restrict__ Wih, const float* __restrict__ Whh,
    const float* __restrict__ bih, const float* __restrict__ bhh,
    u16* __restrict__ qh, u16* __restrict__ vh, u16* __restrict__ nwh)
{
    int bid = blockIdx.x;
    if (bid < BH_) {
        // ---- RNN role: single wave, no barriers ----
        if (threadIdx.x >= 64) return;
        __shared__ __align__(16) u16 hl[D_];
        const int b = bid >> 4, h = bid & 15;
        const int e = threadIdx.x;

        const f32x4* wi4 = (const f32x4*)(Wih + ((size_t)h * D_ + e) * D_);
        const f32x4* wh4 = (const f32x4*)(Whh + ((size_t)h * D_ + e) * D_);
        const float c = bih[h * D_ + e] + bhh[h * D_ + e];

        // step-1 matrix (Wih only) and recurrent matrix (Wih+Whh): named SSA
        f16x8 n0 = pack8(wi4[0],  wi4[1]),  n1 = pack8(wi4[2],  wi4[3]);
        f16x8 n2 = pack8(wi4[4],  wi4[5]),  n3 = pack8(wi4[6],  wi4[7]);
        f16x8 n4 = pack8(wi4[8],  wi4[9]),  n5 = pack8(wi4[10], wi4[11]);
        f16x8 n6 = pack8(wi4[12], wi4[13]), n7 = pack8(wi4[14], wi4[15]);
        f16x8 m0 = pack8(wi4[0]+wh4[0],   wi4[1]+wh4[1]);
        f16x8 m1 = pack8(wi4[2]+wh4[2],   wi4[3]+wh4[3]);
        f16x8 m2 = pack8(wi4[4]+wh4[4],   wi4[5]+wh4[5]);
        f16x8 m3 = pack8(wi4[6]+wh4[6],   wi4[7]+wh4[7]);
        f16x8 m4 = pack8(wi4[8]+wh4[8],   wi4[9]+wh4[9]);
        f16x8 m5 = pack8(wi4[10]+wh4[10], wi4[11]+wh4[11]);
        f16x8 m6 = pack8(wi4[12]+wh4[12], wi4[13]+wh4[13]);
        f16x8 m7 = pack8(wi4[14]+wh4[14], wi4[15]+wh4[15]);

        hl[e] = f2h(tgt[(size_t)b * T_ * E_ + h * D_ + e]);  // k0

        u16* nwp = nwh + (size_t)bid * T_ * D_;
        const f16x8* hl8 = (const f16x8*)hl;

        // ---- step 1: h1 = tanh(Wih k0 + c) ----
        {
            f16x8 x0=hl8[0],x1=hl8[1],x2=hl8[2],x3=hl8[3],
                  x4=hl8[4],x5=hl8[5],x6=hl8[6],x7=hl8[7];
            float s0=dot8(n0,x0,c),   s1=dot8(n1,x1,0.f),
                  s2=dot8(n2,x2,0.f), s3=dot8(n3,x3,0.f),
                  s4=dot8(n4,x4,0.f), s5=dot8(n5,x5,0.f),
                  s6=dot8(n6,x6,0.f), s7=dot8(n7,x7,0.f);
            float hv = ftanh(((s0+s1)+(s2+s3)) + ((s4+s5)+(s6+s7)));
            u16 hb = f2h(hv);
            hl[e] = hb;
            nwp[e] = hb;
        }

        #pragma unroll 1
        for (int t = 1; t < T_; ++t) {
            f16x8 x0=hl8[0],x1=hl8[1],x2=hl8[2],x3=hl8[3],
                  x4=hl8[4],x5=hl8[5],x6=hl8[6],x7=hl8[7];
            float s0=dot8(m0,x0,c),   s1=dot8(m1,x1,0.f),
                  s2=dot8(m2,x2,0.f), s3=dot8(m3,x3,0.f),
                  s4=dot8(m4,x4,0.f), s5=dot8(m5,x5,0.f),
                  s6=dot8(m6,x6,0.f), s7=dot8(m7,x7,0.f);
            float hv = ftanh(((s0+s1)+(s2+s3)) + ((s4+s5)+(s6+s7)));
            u16 hb = f2h(hv);
            hl[e] = hb;
            nwp[(size_t)t * D_ + e] = hb;
        }
    } else {
        // ---- projection role: one thread per (b,h,t,e) ----
        int id = (bid - BH_) * 256 + threadIdx.x;
        int e = id & 63;
        int t = (id >> 6) & 1023;
        int h = (id >> 16) & 15;
        int b = id >> 20;
        const float* srow = src + ((size_t)b * T_ + t) * E_ + h * D_;
        const float* trow = tgt + ((size_t)b * T_ + t) * E_ + h * D_;
        const float* wq = Wq + (size_t)h * D_ * D_ + e;
        const float* wv = Wv + (size_t)h * D_ * D_ + e;
        float aq = 0.f, av = 0.f;
        #pragma unroll 8
        for (int d = 0; d < D_; ++d) {
            aq += srow[d] * wq[(size_t)d * D_];
            av += trow[d] * wv[(size_t)d * D_];
        }
        size_t o = (((size_t)b * H_ + h) * T_ + t) * D_ + e;
        qh[o] = f2h(aq * (1.0f / 256.0f));   // fold 1/(sqrt(D)*sqrt(T)) into q
        vh[o] = f2h(av);
    }
}

// ---------------------------------------------------------------------------
// Kernel 2: flash attention, f16 MFMA 16x16x32, fused output projection.
// Block = 256 threads (4 waves); wave w owns q rows [16w,16w+16). K tiles of
// 64 keys. LDS 16B-chunk XOR swizzle: (row,col) -> row*64+((col>>3 ^ row&7)*8)
// +(col&7). After the K loop, Wo^T (f16) is staged into Klds and O*Wo is done
// with 8 more MFMAs per wave (kills the separate oproj kernel + 64MB traffic).
// ---------------------------------------------------------------------------
#define MFMA16(a, b, c) __builtin_amdgcn_mfma_f32_16x16x32_f16(a, b, c, 0, 0, 0)

__global__ __launch_bounds__(256) void attn_kernel(
    const u16* __restrict__ qh,   // [BH][T][64] f16, pre-scaled 1/256
    const u16* __restrict__ kh,   // nw states  [BH][T][64] f16
    const u16* __restrict__ vh,   // [BH][T][64] f16
    const float* __restrict__ Wo, // [H][64][64] fp32
    float* __restrict__ out)      // [B][T][E] fp32
{
    __shared__ __align__(16) u16 Klds[64 * 64];     // keys; later Wo^T
    __shared__ __align__(16) u16 Vlds[64 * 64];     // V^T: row=d, col=key
    __shared__ __align__(16) u16 Plds[4][16 * 64];  // per-wave P / O relayout

    const int tid  = threadIdx.x;
    const int lane = tid & 63;
    const int w    = tid >> 6;
    const int l15  = lane & 15;
    const int quad = lane >> 4;
    const int sw   = lane & 7;
    const int bh   = blockIdx.y;
    const int qt   = blockIdx.x;

    const size_t base = (size_t)bh * T_ * D_;

    f16x8 aq0, aq1;
    {
        int qrow = qt * 64 + w * 16 + l15;
        const f16x8* qp = (const f16x8*)(qh + base + (size_t)qrow * 64 + quad * 8);
        aq0 = qp[0];
        aq1 = qp[4];
    }

    f32x4 oacc[4];
    #pragma unroll
    for (int i = 0; i < 4; ++i) oacc[i] = (f32x4){0.f, 0.f, 0.f, 0.f};
    float mrun[4], lrun[4];
    #pragma unroll
    for (int r = 0; r < 4; ++r) { mrun[r] = -1e30f; lrun[r] = 0.f; }

    u16* Pw = Plds[w];

    #pragma unroll 1
    for (int kt = 0; kt < 16; ++kt) {
        // ---- stage K (swizzled) and V (transposed, swizzled) ----
        #pragma unroll
        for (int i = 0; i < 2; ++i) {
            int ch = tid + 256 * i;
            int r = ch >> 3, cc = ch & 7;
            short8 val = *(const short8*)(kh + base + (size_t)(kt * 64 + r) * 64 + cc * 8);
            *(short8*)&Klds[r * 64 + ((cc ^ (r & 7)) * 8)] = val;
        }
        #pragma unroll
        for (int i = 0; i < 2; ++i) {
            int ch = tid + 256 * i;
            int r = ch >> 3, cc = ch & 7;
            short8 val = *(const short8*)(vh + base + (size_t)(kt * 64 + r) * 64 + cc * 8);
            #pragma unroll
            for (int j = 0; j < 8; ++j) {
                int d = cc * 8 + j;
                Vlds[d * 64 + (((r >> 3) ^ (d & 7)) * 8) + (r & 7)] = (u16)val[j];
            }
        }
        __syncthreads();

        // ---- S = Q K^T ----
        f32x4 sacc[4];
        #pragma unroll
        for (int u = 0; u < 4; ++u) {
            sacc[u] = (f32x4){0.f, 0.f, 0.f, 0.f};
            int row = 16 * u + l15;
            f16x8 bk0 = *(const f16x8*)&Klds[row * 64 + (((quad + 0) ^ sw) * 8)];
            f16x8 bk1 = *(const f16x8*)&Klds[row * 64 + (((quad + 4) ^ sw) * 8)];
            sacc[u] = MFMA16(aq0, bk0, sacc[u]);
            sacc[u] = MFMA16(aq1, bk1, sacc[u]);
        }

        // ---- online softmax ----
        float al[4];
        float pX[4][4];
        #pragma unroll
        for (int r = 0; r < 4; ++r) {
            float rm = fmaxf(fmaxf(sacc[0][r], sacc[1][r]), fmaxf(sacc[2][r], sacc[3][r]));
            #pragma unroll
            for (int off = 1; off < 16; off <<= 1)
                rm = fmaxf(rm, __shfl_xor(rm, off, 16));
            float mn = fmaxf(mrun[r], rm);
            al[r] = __expf(mrun[r] - mn);
            mrun[r] = mn;
            float rs = 0.f;
            #pragma unroll
            for (int u = 0; u < 4; ++u) {
                float pv = __expf(sacc[u][r] - mn);
                pX[u][r] = pv;
                rs += pv;
            }
            #pragma unroll
            for (int off = 1; off < 16; off <<= 1)
                rs += __shfl_xor(rs, off, 16);
            lrun[r] = lrun[r] * al[r] + rs;
        }
        #pragma unroll
        for (int u = 0; u < 4; ++u)
            #pragma unroll
            for (int r = 0; r < 4; ++r) oacc[u][r] *= al[r];

        // ---- P -> per-wave LDS (C-layout -> A-fragment layout) ----
        #pragma unroll
        for (int u = 0; u < 4; ++u) {
            int col = 16 * u + l15;
            #pragma unroll
            for (int r = 0; r < 4; ++r) {
                int row = quad * 4 + r;
                Pw[row * 64 + (((col >> 3) ^ (row & 7)) * 8) + (col & 7)] = f2h(pX[u][r]);
            }
        }

        // ---- O += P V ----
        #pragma unroll
        for (int kc = 0; kc < 2; ++kc) {
            f16x8 ap = *(const f16x8*)&Pw[l15 * 64 + (((quad + 4 * kc) ^ sw) * 8)];
            #pragma unroll
            for (int nt = 0; nt < 4; ++nt) {
                int drow = 16 * nt + l15;
                f16x8 bv = *(const f16x8*)&Vlds[drow * 64 + (((quad + 4 * kc) ^ sw) * 8)];
                oacc[nt] = MFMA16(ap, bv, oacc[nt]);
            }
        }
        __syncthreads();
    }

    // ---- fused output projection: out_tile = (O/l) * Wo[h] ----
    const int b  = bh >> 4, hh = bh & 15;
    // stage Wo^T (f16, swizzled) into Klds: WoT[e][d] = Wo[h][d][e]
    {
        const float* wo = Wo + (size_t)hh * D_ * D_;
        #pragma unroll
        for (int i = 0; i < 2; ++i) {
            int ch = tid + 256 * i;          // 512 chunks: e = ch>>3, dc = ch&7
            int e = ch >> 3, dc = ch & 7;
            short8 vch;
            #pragma unroll
            for (int j = 0; j < 8; ++j)
                vch[j] = (short)f2h(wo[(size_t)(dc * 8 + j) * D_ + e]);
            *(short8*)&Klds[e * 64 + ((dc ^ (e & 7)) * 8)] = vch;
        }
    }
    // O: normalize, cast f16, C-layout -> A-layout via per-wave Pw
    #pragma unroll
    for (int nt = 0; nt < 4; ++nt) {
        int col = 16 * nt + l15;             // d
        #pragma unroll
        for (int r = 0; r < 4; ++r) {
            int row = quad * 4 + r;          // q
            Pw[row * 64 + (((col >> 3) ^ (row & 7)) * 8) + (col & 7)] =
                f2h(oacc[nt][r] / lrun[r]);
        }
    }
    __syncthreads();    // Wo^T staging visible to all waves (Pw is same-wave)

    f16x8 ao0 = *(const f16x8*)&Pw[l15 * 64 + (((quad + 0) ^ sw) * 8)];
    f16x8 ao1 = *(const f16x8*)&Pw[l15 * 64 + (((quad + 4) ^ sw) * 8)];
    f32x4 oo[4];
    #pragma unroll
    for (int nt = 0; nt < 4; ++nt) {
        oo[nt] = (f32x4){0.f, 0.f, 0.f, 0.f};
        int erow = 16 * nt + l15;
        f16x8 b0 = *(const f16x8*)&Klds[erow * 64 + (((quad + 0) ^ (erow & 7)) * 8)];
        f16x8 b1 = *(const f16x8*)&Klds[erow * 64 + (((quad + 4) ^ (erow & 7)) * 8)];
        oo[nt] = MFMA16(ao0, b0, oo[nt]);
        oo[nt] = MFMA16(ao1, b1, oo[nt]);
    }
    #pragma unroll
    for (int nt = 0; nt < 4; ++nt) {
        #pragma unroll
        for (int r = 0; r < 4; ++r) {
            int qg = qt * 64 + w * 16 + quad * 4 + r;
            int e  = 16 * nt + l15;
            out[((size_t)b * T_ + qg) * E_ + hh * D_ + e] = oo[nt][r];
        }
    }
}

// ---------------------------------------------------------------------------
extern "C" void kernel_launch(void* const* d_in, const int* in_sizes, int n_in,
                              void* d_out, int out_size, void* d_ws, size_t ws_size,
                              hipStream_t stream)
{
    const float* src = (const float*)d_in[0];
    const float* tgt = (const float*)d_in[1];
    const float* Wq  = (const float*)d_in[2];
    const float* Wv  = (const float*)d_in[3];
    const float* Wo  = (const float*)d_in[4];
    const float* Wih = (const float*)d_in[5];
    const float* Whh = (const float*)d_in[6];
    const float* bih = (const float*)d_in[7];
    const float* bhh = (const float*)d_in[8];
    float* out = (float*)d_out;

    char* ws = (char*)d_ws;
    u16* qh  = (u16*)(ws);
    u16* vh  = (u16*)(ws + (size_t)16 * 1024 * 1024);
    u16* nwh = (u16*)(ws + (size_t)32 * 1024 * 1024);

    (void)in_sizes; (void)n_in; (void)out_size; (void)ws_size;

    proj_rnn_kernel<<<dim3(BH_ + 32768), 256, 0, stream>>>(
        src, tgt, Wq, Wv, Wih, Whh, bih, bhh, qh, vh, nwh);
    attn_kernel<<<dim3(16, BH_), 256, 0, stream>>>(qh, nwh, vh, Wo, out);
}

// Round 4
// 397.267 us; speedup vs baseline: 2.0681x; 1.3019x over previous
//
#include <hip/hip_runtime.h>

typedef unsigned short u16;
typedef short short8 __attribute__((ext_vector_type(8)));
typedef float f32x4 __attribute__((ext_vector_type(4)));
typedef _Float16 f16;
typedef f16 f16x2 __attribute__((ext_vector_type(2)));
typedef f16 f16x8 __attribute__((ext_vector_type(8)));

#define B_ 8
#define T_ 1024
#define E_ 1024
#define H_ 16
#define D_ 64
#define BH_ 128

__device__ __forceinline__ float ftanh(float x){
    x = fminf(8.0f, fmaxf(-8.0f, x));
    float e2 = __expf(2.0f * x);
    return 1.0f - 2.0f * __builtin_amdgcn_rcpf(e2 + 1.0f);
}

__device__ __forceinline__ u16 f2h(float x){
    union { f16 h; u16 u; } v; v.h = (f16)x; return v.u;
}

__device__ __forceinline__ float dot8(f16x8 a, f16x8 b, float acc){
#if __has_builtin(__builtin_amdgcn_fdot2)
    f16x2 a0 = {a[0],a[1]}, a1 = {a[2],a[3]}, a2 = {a[4],a[5]}, a3 = {a[6],a[7]};
    f16x2 b0 = {b[0],b[1]}, b1 = {b[2],b[3]}, b2 = {b[4],b[5]}, b3 = {b[6],b[7]};
    acc = __builtin_amdgcn_fdot2(a0, b0, acc, false);
    acc = __builtin_amdgcn_fdot2(a1, b1, acc, false);
    acc = __builtin_amdgcn_fdot2(a2, b2, acc, false);
    acc = __builtin_amdgcn_fdot2(a3, b3, acc, false);
#else
    #pragma unroll
    for (int i = 0; i < 8; ++i) acc += (float)a[i] * (float)b[i];
#endif
    return acc;
}

__device__ __forceinline__ f16x8 pack8(f32x4 a, f32x4 b){
    f16x8 r;
    r[0]=(f16)a[0]; r[1]=(f16)a[1]; r[2]=(f16)a[2]; r[3]=(f16)a[3];
    r[4]=(f16)b[0]; r[5]=(f16)b[1]; r[6]=(f16)b[2]; r[7]=(f16)b[3];
    return r;
}

// Opaque register pin: an asm output cannot be rematerialized, forcing the
// value to stay VGPR-resident across the 1023-step loop (rounds 1-3: VGPR
// counts 52/56/60 proved the allocator reloaded the weights every step).
#define PIN8(x) do { f32x4 _t = __builtin_bit_cast(f32x4, x); \
                     asm volatile("" : "+v"(_t));             \
                     x = __builtin_bit_cast(f16x8, _t); } while (0)

// ---------------------------------------------------------------------------
// Kernel 1: fused RNN (blocks 0..127) + q/v projection (blocks 128..).
// RNN: single wave, matrices pinned in VGPRs, h state via LDS broadcast.
// Proj: block = one (b,h) x 32 t-rows. Thread: e = lane, 8 consecutive t.
//   q written [bh][t][d] (coalesced u16 per row), v written TRANSPOSED
//   [bh][d][t] as one b128 per thread -- so attn can stage V^T vectorized.
// ---------------------------------------------------------------------------
__global__ __launch_bounds__(256, 1) void proj_rnn_kernel(
    const float* __restrict__ src, const float* __restrict__ tgt,
    const float* __restrict__ Wq,  const float* __restrict__ Wv,
    const float* __restrict__ Wih, const float* __restrict__ Whh,
    const float* __restrict__ bih, const float* __restrict__ bhh,
    u16* __restrict__ qh, u16* __restrict__ vh, u16* __restrict__ nwh)
{
    int bid = blockIdx.x;
    if (bid < BH_) {
        // ---- RNN role: single wave, no barriers ----
        if (threadIdx.x >= 64) return;
        __shared__ __align__(16) u16 hl[D_];
        const int b = bid >> 4, h = bid & 15;
        const int e = threadIdx.x;

        const f32x4* wi4 = (const f32x4*)(Wih + ((size_t)h * D_ + e) * D_);
        const f32x4* wh4 = (const f32x4*)(Whh + ((size_t)h * D_ + e) * D_);
        float c = bih[h * D_ + e] + bhh[h * D_ + e];
        asm volatile("" : "+v"(c));

        // step-1 matrix (Wih only): used once, not pinned
        f16x8 n0 = pack8(wi4[0],  wi4[1]),  n1 = pack8(wi4[2],  wi4[3]);
        f16x8 n2 = pack8(wi4[4],  wi4[5]),  n3 = pack8(wi4[6],  wi4[7]);
        f16x8 n4 = pack8(wi4[8],  wi4[9]),  n5 = pack8(wi4[10], wi4[11]);
        f16x8 n6 = pack8(wi4[12], wi4[13]), n7 = pack8(wi4[14], wi4[15]);
        // recurrent matrix (Wih+Whh): pinned resident
        f16x8 m0 = pack8(wi4[0]+wh4[0],   wi4[1]+wh4[1]);
        f16x8 m1 = pack8(wi4[2]+wh4[2],   wi4[3]+wh4[3]);
        f16x8 m2 = pack8(wi4[4]+wh4[4],   wi4[5]+wh4[5]);
        f16x8 m3 = pack8(wi4[6]+wh4[6],   wi4[7]+wh4[7]);
        f16x8 m4 = pack8(wi4[8]+wh4[8],   wi4[9]+wh4[9]);
        f16x8 m5 = pack8(wi4[10]+wh4[10], wi4[11]+wh4[11]);
        f16x8 m6 = pack8(wi4[12]+wh4[12], wi4[13]+wh4[13]);
        f16x8 m7 = pack8(wi4[14]+wh4[14], wi4[15]+wh4[15]);
        PIN8(m0); PIN8(m1); PIN8(m2); PIN8(m3);
        PIN8(m4); PIN8(m5); PIN8(m6); PIN8(m7);

        hl[e] = f2h(tgt[(size_t)b * T_ * E_ + h * D_ + e]);  // k0

        u16* nwp = nwh + (size_t)bid * T_ * D_;
        const f16x8* hl8 = (const f16x8*)hl;

        // ---- step 1: h1 = tanh(Wih k0 + c) ----
        {
            f16x8 x0=hl8[0],x1=hl8[1],x2=hl8[2],x3=hl8[3],
                  x4=hl8[4],x5=hl8[5],x6=hl8[6],x7=hl8[7];
            float s0=dot8(n0,x0,c),   s1=dot8(n1,x1,0.f),
                  s2=dot8(n2,x2,0.f), s3=dot8(n3,x3,0.f),
                  s4=dot8(n4,x4,0.f), s5=dot8(n5,x5,0.f),
                  s6=dot8(n6,x6,0.f), s7=dot8(n7,x7,0.f);
            float hv = ftanh(((s0+s1)+(s2+s3)) + ((s4+s5)+(s6+s7)));
            u16 hb = f2h(hv);
            hl[e] = hb;
            nwp[e] = hb;
        }

        #pragma unroll 1
        for (int t = 1; t < T_; ++t) {
            f16x8 x0=hl8[0],x1=hl8[1],x2=hl8[2],x3=hl8[3],
                  x4=hl8[4],x5=hl8[5],x6=hl8[6],x7=hl8[7];
            float s0=dot8(m0,x0,c),   s1=dot8(m1,x1,0.f),
                  s2=dot8(m2,x2,0.f), s3=dot8(m3,x3,0.f),
                  s4=dot8(m4,x4,0.f), s5=dot8(m5,x5,0.f),
                  s6=dot8(m6,x6,0.f), s7=dot8(m7,x7,0.f);
            float hv = ftanh(((s0+s1)+(s2+s3)) + ((s4+s5)+(s6+s7)));
            u16 hb = f2h(hv);
            hl[e] = hb;
            nwp[(size_t)t * D_ + e] = hb;
        }
    } else {
        // ---- projection role ----
        int pb   = bid - BH_;          // 0 .. 4095
        int bh   = pb >> 5;            // (b*16+h)
        int tile = pb & 31;            // 32 t-rows per block
        int b = bh >> 4, h = bh & 15;
        int e  = threadIdx.x & 63;
        int tg = threadIdx.x >> 6;
        int t0 = tile * 32 + tg * 8;

        const float* wq = Wq + (size_t)h * D_ * D_ + e;  // column e, stride 64
        const float* wv = Wv + (size_t)h * D_ * D_ + e;
        const float* s0 = src + ((size_t)b * T_ + t0) * E_ + h * D_;
        const float* g0 = tgt + ((size_t)b * T_ + t0) * E_ + h * D_;

        float aq[8] = {0,0,0,0,0,0,0,0};
        float av[8] = {0,0,0,0,0,0,0,0};
        #pragma unroll 4
        for (int d4 = 0; d4 < 16; ++d4) {
            float q0 = wq[(4*d4+0)*64], q1 = wq[(4*d4+1)*64],
                  q2 = wq[(4*d4+2)*64], q3 = wq[(4*d4+3)*64];
            float v0 = wv[(4*d4+0)*64], v1 = wv[(4*d4+1)*64],
                  v2 = wv[(4*d4+2)*64], v3 = wv[(4*d4+3)*64];
            #pragma unroll
            for (int j = 0; j < 8; ++j) {
                float4 x = *(const float4*)(s0 + (size_t)j * E_ + 4*d4);
                float4 y = *(const float4*)(g0 + (size_t)j * E_ + 4*d4);
                aq[j] += x.x*q0 + x.y*q1 + x.z*q2 + x.w*q3;
                av[j] += y.x*v0 + y.y*v1 + y.z*v2 + y.w*v3;
            }
        }
        // q: [bh][t][e], coalesced u16 rows; fold 1/256 score scale into q
        u16* qp = qh + ((size_t)bh * T_ + t0) * D_ + e;
        #pragma unroll
        for (int j = 0; j < 8; ++j) qp[(size_t)j * D_] = f2h(aq[j] * (1.0f/256.0f));
        // v: TRANSPOSED [bh][d=e][t], one b128 per thread
        f16x8 vv;
        #pragma unroll
        for (int j = 0; j < 8; ++j) vv[j] = (f16)av[j];
        *(f16x8*)(vh + ((size_t)bh * D_ + e) * T_ + t0) = vv;
    }
}

// ---------------------------------------------------------------------------
// Kernel 2: flash attention, f16 MFMA 16x16x32, fused output projection.
// Block = 256 threads (4 waves); wave w owns q rows [16w,16w+16). K tiles of
// 64 keys. V arrives PRE-TRANSPOSED [bh][d][t] so both K and V^T stage as
// vectorized b128 (round-3 scalar V transpose had ~16-way bank conflicts).
// No softmax max: logits |s|~0.006 (q pre-scaled 1/256), shift-invariant.
// LDS swizzle: (row,col) -> row*64 + ((col>>3 ^ (row&7))*8) + (col&7).
// ---------------------------------------------------------------------------
#define MFMA16(a, b, c) __builtin_amdgcn_mfma_f32_16x16x32_f16(a, b, c, 0, 0, 0)

__global__ __launch_bounds__(256) void attn_kernel(
    const u16* __restrict__ qh,   // [bh][t][64] f16, pre-scaled 1/256
    const u16* __restrict__ kh,   // nw states [bh][t][64] f16
    const u16* __restrict__ vh,   // V^T [bh][d][t] f16
    const float* __restrict__ Wo, // [H][64][64] fp32
    float* __restrict__ out)      // [B][T][E] fp32
{
    __shared__ __align__(16) u16 Klds[64 * 64];     // keys; later Wo^T
    __shared__ __align__(16) u16 Vlds[64 * 64];     // V^T: row=d, col=key
    __shared__ __align__(16) u16 Plds[4][16 * 64];  // per-wave P / O relayout

    const int tid  = threadIdx.x;
    const int lane = tid & 63;
    const int w    = tid >> 6;
    const int l15  = lane & 15;
    const int quad = lane >> 4;
    const int sw   = lane & 7;
    const int bh   = blockIdx.y;
    const int qt   = blockIdx.x;

    const size_t base  = (size_t)bh * T_ * D_;
    const size_t vbase = (size_t)bh * D_ * T_;

    f16x8 aq0, aq1;
    {
        int qrow = qt * 64 + w * 16 + l15;
        const f16x8* qp = (const f16x8*)(qh + base + (size_t)qrow * 64 + quad * 8);
        aq0 = qp[0];
        aq1 = qp[4];
    }

    f32x4 oacc[4];
    #pragma unroll
    for (int i = 0; i < 4; ++i) oacc[i] = (f32x4){0.f, 0.f, 0.f, 0.f};
    float lrun[4] = {0.f, 0.f, 0.f, 0.f};

    u16* Pw = Plds[w];

    #pragma unroll 1
    for (int kt = 0; kt < 16; ++kt) {
        // ---- stage K rows + V^T rows, both vectorized b128, swizzled ----
        #pragma unroll
        for (int i = 0; i < 2; ++i) {
            int ch = tid + 256 * i;          // 512 chunks of 8 u16
            int r = ch >> 3, cc = ch & 7;
            short8 kval = *(const short8*)(kh + base + (size_t)(kt * 64 + r) * 64 + cc * 8);
            *(short8*)&Klds[r * 64 + ((cc ^ (r & 7)) * 8)] = kval;
            short8 vval = *(const short8*)(vh + vbase + (size_t)r * T_ + kt * 64 + cc * 8);
            *(short8*)&Vlds[r * 64 + ((cc ^ (r & 7)) * 8)] = vval;
        }
        __syncthreads();

        // ---- S = Q K^T ----
        f32x4 sacc[4];
        #pragma unroll
        for (int u = 0; u < 4; ++u) {
            sacc[u] = (f32x4){0.f, 0.f, 0.f, 0.f};
            int row = 16 * u + l15;
            f16x8 bk0 = *(const f16x8*)&Klds[row * 64 + (((quad + 0) ^ sw) * 8)];
            f16x8 bk1 = *(const f16x8*)&Klds[row * 64 + (((quad + 4) ^ sw) * 8)];
            sacc[u] = MFMA16(aq0, bk0, sacc[u]);
            sacc[u] = MFMA16(aq1, bk1, sacc[u]);
        }

        // ---- softmax accumulation (no max: shift-invariant, |s| tiny) ----
        float pr[4][4];
        #pragma unroll
        for (int r = 0; r < 4; ++r) {
            float rs = 0.f;
            #pragma unroll
            for (int u = 0; u < 4; ++u) {
                float pv = __expf(sacc[u][r]);
                pr[u][r] = pv;
                rs += pv;
            }
            #pragma unroll
            for (int off = 1; off < 16; off <<= 1)
                rs += __shfl_xor(rs, off, 16);
            lrun[r] += rs;
        }

        // ---- P -> per-wave LDS (C-layout -> A-fragment layout) ----
        #pragma unroll
        for (int u = 0; u < 4; ++u) {
            int col = 16 * u + l15;
            #pragma unroll
            for (int r = 0; r < 4; ++r) {
                int row = quad * 4 + r;
                Pw[row * 64 + (((col >> 3) ^ (row & 7)) * 8) + (col & 7)] = f2h(pr[u][r]);
            }
        }

        // ---- O += P V ----
        #pragma unroll
        for (int kc = 0; kc < 2; ++kc) {
            f16x8 ap = *(const f16x8*)&Pw[l15 * 64 + (((quad + 4 * kc) ^ sw) * 8)];
            #pragma unroll
            for (int nt = 0; nt < 4; ++nt) {
                int drow = 16 * nt + l15;
                f16x8 bv = *(const f16x8*)&Vlds[drow * 64 + (((quad + 4 * kc) ^ sw) * 8)];
                oacc[nt] = MFMA16(ap, bv, oacc[nt]);
            }
        }
        __syncthreads();
    }

    // ---- fused output projection: out_tile = (O/l) * Wo[h] ----
    const int b  = bh >> 4, hh = bh & 15;
    {
        const float* wo = Wo + (size_t)hh * D_ * D_;
        #pragma unroll
        for (int i = 0; i < 2; ++i) {
            int ch = tid + 256 * i;          // e = ch>>3, dc = ch&7
            int e = ch >> 3, dc = ch & 7;
            short8 vch;
            #pragma unroll
            for (int j = 0; j < 8; ++j)
                vch[j] = (short)f2h(wo[(size_t)(dc * 8 + j) * D_ + e]);
            *(short8*)&Klds[e * 64 + ((dc ^ (e & 7)) * 8)] = vch;
        }
    }
    #pragma unroll
    for (int nt = 0; nt < 4; ++nt) {
        int col = 16 * nt + l15;             // d
        #pragma unroll
        for (int r = 0; r < 4; ++r) {
            int row = quad * 4 + r;          // q
            Pw[row * 64 + (((col >> 3) ^ (row & 7)) * 8) + (col & 7)] =
                f2h(oacc[nt][r] / lrun[r]);
        }
    }
    __syncthreads();    // Wo^T staging visible to all waves

    f16x8 ao0 = *(const f16x8*)&Pw[l15 * 64 + (((quad + 0) ^ sw) * 8)];
    f16x8 ao1 = *(const f16x8*)&Pw[l15 * 64 + (((quad + 4) ^ sw) * 8)];
    f32x4 oo[4];
    #pragma unroll
    for (int nt = 0; nt < 4; ++nt) {
        oo[nt] = (f32x4){0.f, 0.f, 0.f, 0.f};
        int erow = 16 * nt + l15;
        f16x8 b0 = *(const f16x8*)&Klds[erow * 64 + (((quad + 0) ^ (erow & 7)) * 8)];
        f16x8 b1 = *(const f16x8*)&Klds[erow * 64 + (((quad + 4) ^ (erow & 7)) * 8)];
        oo[nt] = MFMA16(ao0, b0, oo[nt]);
        oo[nt] = MFMA16(ao1, b1, oo[nt]);
    }
    #pragma unroll
    for (int nt = 0; nt < 4; ++nt) {
        #pragma unroll
        for (int r = 0; r < 4; ++r) {
            int qg = qt * 64 + w * 16 + quad * 4 + r;
            int e  = 16 * nt + l15;
            out[((size_t)b * T_ + qg) * E_ + hh * D_ + e] = oo[nt][r];
        }
    }
}

// ---------------------------------------------------------------------------
extern "C" void kernel_launch(void* const* d_in, const int* in_sizes, int n_in,
                              void* d_out, int out_size, void* d_ws, size_t ws_size,
                              hipStream_t stream)
{
    const float* src = (const float*)d_in[0];
    const float* tgt = (const float*)d_in[1];
    const float* Wq  = (const float*)d_in[2];
    const float* Wv  = (const float*)d_in[3];
    const float* Wo  = (const float*)d_in[4];
    const float* Wih = (const float*)d_in[5];
    const float* Whh = (const float*)d_in[6];
    const float* bih = (const float*)d_in[7];
    const float* bhh = (const float*)d_in[8];
    float* out = (float*)d_out;

    char* ws = (char*)d_ws;
    u16* qh  = (u16*)(ws);                             // [bh][t][d] 16 MB
    u16* vh  = (u16*)(ws + (size_t)16 * 1024 * 1024);  // V^T [bh][d][t] 16 MB
    u16* nwh = (u16*)(ws + (size_t)32 * 1024 * 1024);  // [bh][t][d] 16 MB

    (void)in_sizes; (void)n_in; (void)out_size; (void)ws_size;

    // blocks [0,128) = RNN chains; [128, 128+4096) = q/v projection
    proj_rnn_kernel<<<dim3(BH_ + 4096), 256, 0, stream>>>(
        src, tgt, Wq, Wv, Wih, Whh, bih, bhh, qh, vh, nwh);
    attn_kernel<<<dim3(16, BH_), 256, 0, stream>>>(qh, nwh, vh, Wo, out);
}